// Round 2
// baseline (1484.187 us; speedup 1.0000x reference)
//
#include <hip/hip_runtime.h>
#include <hip/hip_bf16.h>
#include <math.h>

#define N_NODES 100000
#define N_EDGES 3200000
#define IN_DIM  1433
#define HID     16
#define NCLS    40
#define KPAD    1536   // IN_DIM padded to 12*128 for the k-loop

// ---------------- degree / norm ----------------

__global__ void k_deg_init(float* __restrict__ deg) {
    int i = blockIdx.x * blockDim.x + threadIdx.x;
    if (i < N_NODES) deg[i] = 1.0f;   // self-loop contribution
}

// edge_index arrives as int32 (harness converts integer inputs): [2][E] flat.
__global__ void k_deg_accum(const int* __restrict__ ei, float* __restrict__ deg) {
    int stride = gridDim.x * blockDim.x;
    for (int e = blockIdx.x * blockDim.x + threadIdx.x; e < N_EDGES; e += stride) {
        int d = ei[N_EDGES + e];      // dst row
        atomicAdd(&deg[d], 1.0f);
    }
}

__global__ void k_dinv(float* __restrict__ deg) {
    int i = blockIdx.x * blockDim.x + threadIdx.x;
    if (i < N_NODES) deg[i] = 1.0f / sqrtf(deg[i]);   // deg >= 1 always
}

// ---------------- W1 transpose into ws: w1t[j][k], zero-padded to KPAD ----------------

__global__ void k_w1t(const float* __restrict__ W1, float* __restrict__ w1t) {
    int i = blockIdx.x * blockDim.x + threadIdx.x;
    if (i < HID * KPAD) {
        int j = i / KPAD;
        int k = i - j * KPAD;
        w1t[i] = (k < IN_DIM) ? W1[k * HID + j] : 0.0f;
    }
}

// ---------------- GEMM1: xw = x @ W1, h_init = dinv^2 * xw ----------------
// 512 threads (8 waves); wave handles 4 rows. Lane l covers k = 2l + 128*it
// (scalar dword x loads, 8B-stride across lanes -> dense/coalesced).
// W1T read from global (L1/L2-resident, 96 KB). Butterfly-reduce, lanes 0-15 store.

__global__ __launch_bounds__(512) void k_gemm1(const float* __restrict__ x,
                                               const float* __restrict__ w1t,
                                               const float* __restrict__ dinv,
                                               float* __restrict__ xw,
                                               float* __restrict__ h) {
    const int tid  = threadIdx.x;
    const int wave = tid >> 6;
    const int lane = tid & 63;
    const int ntiles = N_NODES / 4;   // 25000, exact

    for (int tile = blockIdx.x * 8 + wave; tile < ntiles; tile += gridDim.x * 8) {
        const int row0 = tile * 4;
        float acc[4][16];
        #pragma unroll
        for (int r = 0; r < 4; ++r)
            #pragma unroll
            for (int j = 0; j < 16; ++j) acc[r][j] = 0.0f;

        const float* xr0 = x + (long)row0 * IN_DIM;

        for (int it = 0; it < KPAD / 128; ++it) {
            const int k = it * 128 + lane * 2;
            float xa[4], xb[4];
            #pragma unroll
            for (int r = 0; r < 4; ++r) {
                const float* xr = xr0 + r * IN_DIM;
                xa[r] = (k     < IN_DIM) ? xr[k]     : 0.0f;
                xb[r] = (k + 1 < IN_DIM) ? xr[k + 1] : 0.0f;
            }
            #pragma unroll
            for (int j = 0; j < 16; ++j) {
                float2 wv = *(const float2*)&w1t[j * KPAD + k];   // 8B-aligned (k even), zero-padded
                #pragma unroll
                for (int r = 0; r < 4; ++r)
                    acc[r][j] += xa[r] * wv.x + xb[r] * wv.y;
            }
        }

        // butterfly reduction over all 64 lanes: every lane ends with the full sum
        #pragma unroll
        for (int r = 0; r < 4; ++r)
            #pragma unroll
            for (int j = 0; j < 16; ++j) {
                float v = acc[r][j];
                v += __shfl_xor(v, 1);
                v += __shfl_xor(v, 2);
                v += __shfl_xor(v, 4);
                v += __shfl_xor(v, 8);
                v += __shfl_xor(v, 16);
                v += __shfl_xor(v, 32);
                acc[r][j] = v;
            }

        if (lane < 16) {
            #pragma unroll
            for (int r = 0; r < 4; ++r) {
                float o = acc[r][0];
                #pragma unroll
                for (int j = 1; j < 16; ++j) o = (lane == j) ? acc[r][j] : o;  // compile-time idx
                const int row = row0 + r;
                const float dv = dinv[row];
                xw[row * HID + lane] = o;
                h[row * HID + lane]  = dv * dv * o;   // fused self-loop init
            }
        }
    }
}

// ---------------- edge scatter-add (16 feats), shared by both layers ----------------

__global__ void k_edge(const int* __restrict__ ei, const float* __restrict__ dinv,
                       const float* __restrict__ src_feat, float* __restrict__ dst_acc) {
    const unsigned total  = (unsigned)N_EDGES * 16u;
    const unsigned stride = gridDim.x * blockDim.x;
    for (unsigned t = blockIdx.x * blockDim.x + threadIdx.x; t < total; t += stride) {
        const unsigned e = t >> 4;
        const unsigned j = t & 15u;
        const int s = ei[e];                    // src row (int32)
        const int d = ei[N_EDGES + e];          // dst row (int32)
        const float w = dinv[s] * dinv[d];
        atomicAdd(&dst_acc[(unsigned)d * 16u + j], src_feat[(unsigned)s * 16u + j] * w);
    }
}

// ---------------- bias+relu on h, fused self-loop init of layer-2 accumulator ----------------

__global__ void k_relu_init2(const float* __restrict__ dinv, const float* __restrict__ b1,
                             float* __restrict__ h, float* __restrict__ out2) {
    int i = blockIdx.x * blockDim.x + threadIdx.x;
    if (i < N_NODES * HID) {
        const int n = i >> 4;
        const int j = i & 15;
        float v = fmaxf(h[i] + b1[j], 0.0f);
        h[i] = v;
        const float dv = dinv[n];
        out2[i] = dv * dv * v;
    }
}

// ---------------- final: (agg2 @ W2) + b2 -> log_softmax ----------------
// Aggregation commutes with the linear map: A(h W2) == (A h) W2, so we aggregated
// 16 features and project to 40 classes here (2.5x less edge traffic/atomics).

__global__ void k_out(const float* __restrict__ agg, const float* __restrict__ W2,
                      const float* __restrict__ b2, float* __restrict__ out) {
    const int n = blockIdx.x * blockDim.x + threadIdx.x;
    if (n >= N_NODES) return;

    float hv[16];
    const float4* ap = (const float4*)(agg + (long)n * HID);   // 64B-aligned
    #pragma unroll
    for (int q = 0; q < 4; ++q) {
        float4 v = ap[q];
        hv[q * 4 + 0] = v.x; hv[q * 4 + 1] = v.y; hv[q * 4 + 2] = v.z; hv[q * 4 + 3] = v.w;
    }

    float acc[NCLS];
    #pragma unroll
    for (int c = 0; c < NCLS; ++c) acc[c] = b2[c];
    #pragma unroll
    for (int k = 0; k < HID; ++k) {
        const float hk = hv[k];
        #pragma unroll
        for (int c = 0; c < NCLS; ++c) acc[c] += hk * W2[k * NCLS + c];  // uniform -> s_load
    }

    float m = acc[0];
    #pragma unroll
    for (int c = 1; c < NCLS; ++c) m = fmaxf(m, acc[c]);
    float ssum = 0.0f;
    #pragma unroll
    for (int c = 0; c < NCLS; ++c) ssum += expf(acc[c] - m);
    const float lse = m + logf(ssum);

    float* op = out + (long)n * NCLS;
    #pragma unroll
    for (int q = 0; q < 10; ++q) {    // 40 floats = 10x float4, 16B-aligned (160B rows)
        float4 v;
        v.x = acc[q * 4 + 0] - lse; v.y = acc[q * 4 + 1] - lse;
        v.z = acc[q * 4 + 2] - lse; v.w = acc[q * 4 + 3] - lse;
        ((float4*)op)[q] = v;
    }
}

// ---------------- launcher ----------------

extern "C" void kernel_launch(void* const* d_in, const int* in_sizes, int n_in,
                              void* d_out, int out_size, void* d_ws, size_t ws_size,
                              hipStream_t stream) {
    const float* x   = (const float*)d_in[0];
    const int*   ei  = (const int*)d_in[1];    // int32 (harness-converted), [2][E] flat
    const float* W1  = (const float*)d_in[2];
    const float* b1  = (const float*)d_in[3];
    const float* W2  = (const float*)d_in[4];
    const float* b2  = (const float*)d_in[5];
    float* out = (float*)d_out;

    // ws layout: deg/dinv [N] | w1t [16*KPAD] | xw [N*16] | h [N*16] | out2 [N*16]  (~19.8 MB)
    float* deg  = (float*)d_ws;
    float* w1t  = deg  + ((N_NODES + 127) & ~127);
    float* xw   = w1t  + HID * KPAD;
    float* h    = xw   + (size_t)N_NODES * HID;
    float* out2 = h    + (size_t)N_NODES * HID;

    k_deg_init <<<(N_NODES + 255) / 256, 256, 0, stream>>>(deg);
    k_deg_accum<<<2048, 256, 0, stream>>>(ei, deg);
    k_dinv     <<<(N_NODES + 255) / 256, 256, 0, stream>>>(deg);
    k_w1t      <<<(HID * KPAD + 255) / 256, 256, 0, stream>>>(W1, w1t);

    k_gemm1<<<1024, 512, 0, stream>>>(x, w1t, deg, xw, h);

    k_edge<<<4096, 256, 0, stream>>>(ei, deg, xw, h);                       // layer 1 aggregate
    k_relu_init2<<<(N_NODES * HID + 255) / 256, 256, 0, stream>>>(deg, b1, h, out2);
    k_edge<<<4096, 256, 0, stream>>>(ei, deg, h, out2);                     // layer 2 aggregate
    k_out<<<(N_NODES + 255) / 256, 256, 0, stream>>>(out2, W2, b2, out);
}